// Round 16
// baseline (139.779 us; speedup 1.0000x reference)
//
#include <hip/hip_runtime.h>
#include <hip/hip_bf16.h>
#include <math.h>

// Problem constants
#define TT 1024      // tokens (B*S)
#define HD 1024      // hidden
#define NE 8         // experts
#define ID 2048      // intermediate
#define MAXSLOT 3072
constexpr float JEPS = 0.01f;

typedef __attribute__((ext_vector_type(8))) short bf16x8;
typedef __attribute__((ext_vector_type(4))) float f32x4;

__device__ __forceinline__ float silu_f(float v) {
    return v / (1.f + expf(-v));
}

__device__ __forceinline__ unsigned short f2bf(float f) {
    unsigned int u = __float_as_uint(f);
    u += 0x7FFF + ((u >> 16) & 1);
    return (unsigned short)(u >> 16);
}

// packed fp32x4 -> bf16x4 store (v_cvt_pk_bf16_f32 path), p 8B aligned
__device__ __forceinline__ void st_bf4(unsigned short* p, float4 v) {
    __hip_bfloat162 lo = __float22bfloat162_rn(make_float2(v.x, v.y));
    __hip_bfloat162 hi = __float22bfloat162_rn(make_float2(v.z, v.w));
    union { __hip_bfloat162 h[2]; uint2 q; } pk;
    pk.h[0] = lo; pk.h[1] = hi;
    *(uint2*)p = pk.q;
}

// ---------------- Kernel 1: gating (one wave per token) + x->bf16 fused ----------------
__global__ __launch_bounds__(256) void gate_kernel(
    const float* __restrict__ x, const float* __restrict__ gw,
    int* __restrict__ sel, float* __restrict__ wgt, int* __restrict__ counts,
    unsigned short* __restrict__ xbf)
{
    int wave = threadIdx.x >> 6;
    int lane = threadIdx.x & 63;
    int t = blockIdx.x * 4 + wave;

    const float4* x4 = (const float4*)(x + (size_t)t * HD);
    const float4* g4 = (const float4*)gw;

    float acc[8] = {0.f,0.f,0.f,0.f,0.f,0.f,0.f,0.f};
    #pragma unroll
    for (int c = 0; c < 4; ++c) {
        float4 xv = x4[lane + c * 64];
        st_bf4(&xbf[(size_t)t * HD + (size_t)(lane + c * 64) * 4], xv);
        #pragma unroll
        for (int e = 0; e < 8; ++e) {
            float4 gv = g4[e * 256 + lane + c * 64];
            acc[e] += xv.x*gv.x + xv.y*gv.y + xv.z*gv.z + xv.w*gv.w;
        }
    }
    #pragma unroll
    for (int e = 0; e < 8; ++e) {
        float v = acc[e];
        #pragma unroll
        for (int off = 32; off > 0; off >>= 1) v += __shfl_xor(v, off, 64);
        acc[e] = v;
    }

    if (lane == 0) {
        float s[8];
        #pragma unroll
        for (int e = 0; e < 8; ++e) s[e] = acc[e];

        int i0 = 0; float t1 = s[0];
        #pragma unroll
        for (int e = 1; e < 8; ++e) { if (s[e] > t1) { t1 = s[e]; i0 = e; } }
        int i1 = -1; float t2 = -INFINITY;
        #pragma unroll
        for (int e = 0; e < 8; ++e) {
            if (e == i0) continue;
            if (s[e] > t2) { t2 = s[e]; i1 = e; }
        }

        float sum1 = 0.f;
        #pragma unroll
        for (int e = 0; e < 8; ++e) {
            if (e == i0) { sum1 += 1.f; continue; }
            float f = fmaxf(fabsf(s[e]), t1);
            bool masked = (t1 - s[e]) > 2.f * JEPS * f;
            if (!masked) sum1 += expf(s[e] - t1);
        }
        float w0 = 1.f / sum1;

        float sum2 = 0.f;
        #pragma unroll
        for (int e = 0; e < 8; ++e) {
            if (e == i0) continue;
            if (e == i1) { sum2 += 1.f; continue; }
            float f = fmaxf(fabsf(s[e]), t2);
            bool masked = (t2 - s[e]) > 2.f * JEPS * f;
            if (!masked) sum2 += expf(s[e] - t2);
        }
        float w1v = 1.f / sum2;

        sel[t * 2 + 0] = i0; sel[t * 2 + 1] = i1;
        wgt[t * 2 + 0] = w0; wgt[t * 2 + 1] = w1v;
        atomicAdd(&counts[i0], 1);
        atomicAdd(&counts[i1], 1);
    }
}

// ---------------- Kernel 2: padded prefix offsets (pad to 128) ----------------
__global__ void offsets_kernel(const int* __restrict__ counts,
                               int* __restrict__ offs, int* __restrict__ cursor)
{
    int o = 0;
    for (int e = 0; e < NE; ++e) {
        offs[e] = o;
        cursor[e] = o;
        o += (counts[e] + 127) & ~127;
    }
}

// ---------------- Kernel 3: scatter tokens to expert slots ----------------
__global__ __launch_bounds__(256) void scatter_kernel(
    const int* __restrict__ sel, const float* __restrict__ wgt,
    int* __restrict__ cursor, int* __restrict__ slot_token,
    float* __restrict__ slot_weight)
{
    int t = blockIdx.x * 256 + threadIdx.x;
    #pragma unroll
    for (int j = 0; j < 2; ++j) {
        int e = sel[t * 2 + j];
        int pos = atomicAdd(&cursor[e], 1);
        slot_token[pos] = t;
        slot_weight[pos] = wgt[t * 2 + j];
    }
}

// ---------------- Kernel 4: FFN1 (it-fast, depth-3, +setprio — proven 76 us) ----------------
// 1D grid 2048: e = bid&7 (XCD), r = bid>>3, it = r&31 (FAST), tt = r>>5.
// Tile 128 slots x 64 intermediate, BK=32, 32 K-steps; 3 reg sets over 2 LDS bufs.
// setprio(1) around MFMA: 2-3 blocks/CU at different phases -> scheduler favors
// the MFMA-phase wave while others issue loads (T5 regime; R15 A/B: 90 -> 76 us).
__global__ __launch_bounds__(256) void ffn1_kernel(
    const unsigned short* __restrict__ xbf, const float* __restrict__ w1,
    const float* __restrict__ w3, const int* __restrict__ counts,
    const int* __restrict__ offs, const int* __restrict__ slot_token,
    unsigned short* __restrict__ act)
{
    int bid = blockIdx.x;
    int e = bid & 7;
    int r = bid >> 3;
    int it = r & 31, tt = r >> 5;
    int cnt = counts[e];
    if (tt * 128 >= cnt) return;
    int base = offs[e];

    __shared__ unsigned short Xs[2][128][40];
    __shared__ unsigned short W1s[2][64][40];
    __shared__ unsigned short W3s[2][64][40];

    int t = threadIdx.x;
    int xr = t >> 1, xs = (t & 1) * 16;
    int srow = tt * 128 + xr;
    int tok = (srow < cnt) ? slot_token[base + srow] : slot_token[base];
    const unsigned short* xptr = xbf + (size_t)tok * HD;
    int wrow = t >> 2, ws0 = t & 3;
    const float* w1ptr = w1 + ((size_t)e * ID + (size_t)it * 64 + wrow) * HD;
    const float* w3ptr = w3 + ((size_t)e * ID + (size_t)it * 64 + wrow) * HD;

    int wid = t >> 6, lane = t & 63;
    int wr = wid >> 1, wc = wid & 1;
    int fr = lane & 15, fg = lane >> 4;

    f32x4 a1[4][2], a3[4][2];
    #pragma unroll
    for (int m = 0; m < 4; ++m)
        #pragma unroll
        for (int n = 0; n < 2; ++n) {
            a1[m][n] = (f32x4){0.f, 0.f, 0.f, 0.f};
            a3[m][n] = (f32x4){0.f, 0.f, 0.f, 0.f};
        }

    // three named register sets (no runtime indexing)
    uint4 Axa, Axb, Bxa, Bxb, Cxa, Cxb;
    float4 Aw1a, Aw1b, Aw3a, Aw3b;
    float4 Bw1a, Bw1b, Bw3a, Bw3b;
    float4 Cw1a, Cw1b, Cw3a, Cw3b;

#define F1_LOAD(S, KT) do { \
    S##xa  = *(const uint4*)(xptr + (KT) + xs); \
    S##xb  = *(const uint4*)(xptr + (KT) + xs + 8); \
    S##w1a = *(const float4*)(w1ptr + (KT) + ws0 * 4); \
    S##w1b = *(const float4*)(w1ptr + (KT) + (ws0 + 4) * 4); \
    S##w3a = *(const float4*)(w3ptr + (KT) + ws0 * 4); \
    S##w3b = *(const float4*)(w3ptr + (KT) + (ws0 + 4) * 4); \
} while (0)
#define F1_STORE(S, B) do { \
    *(uint4*)&Xs[B][xr][xs] = S##xa; \
    *(uint4*)&Xs[B][xr][xs + 8] = S##xb; \
    st_bf4(&W1s[B][wrow][ws0 * 4], S##w1a); \
    st_bf4(&W1s[B][wrow][(ws0 + 4) * 4], S##w1b); \
    st_bf4(&W3s[B][wrow][ws0 * 4], S##w3a); \
    st_bf4(&W3s[B][wrow][(ws0 + 4) * 4], S##w3b); \
} while (0)
#define F1_C(B) do { \
    bf16x8 af[4], b1f[2], b3f[2]; \
    _Pragma("unroll") for (int m = 0; m < 4; ++m) \
        af[m] = *(const bf16x8*)&Xs[B][wr * 64 + m * 16 + fr][fg * 8]; \
    _Pragma("unroll") for (int n = 0; n < 2; ++n) { \
        b1f[n] = *(const bf16x8*)&W1s[B][wc * 32 + n * 16 + fr][fg * 8]; \
        b3f[n] = *(const bf16x8*)&W3s[B][wc * 32 + n * 16 + fr][fg * 8]; } \
    __builtin_amdgcn_s_setprio(1); \
    _Pragma("unroll") for (int m = 0; m < 4; ++m) \
        _Pragma("unroll") for (int n = 0; n < 2; ++n) { \
            a1[m][n] = __builtin_amdgcn_mfma_f32_16x16x32_bf16(af[m], b1f[n], a1[m][n], 0, 0, 0); \
            a3[m][n] = __builtin_amdgcn_mfma_f32_16x16x32_bf16(af[m], b3f[n], a3[m][n], 0, 0, 0); } \
    __builtin_amdgcn_s_setprio(0); \
} while (0)

    // prologue: step0 -> A, step1 -> B; stage A into buf0
    F1_LOAD(A, 0);
    F1_LOAD(B, 32);
    F1_STORE(A, 0);

    // main loop: phases p = 6*o + j, o = 0..4 (steps 0..29); loads reach step 31
    for (int o = 0; o < 5; ++o) {
        int kt = o * 192;
        __syncthreads(); F1_LOAD(C, kt +  64); F1_C(0); F1_STORE(B, 1);  // j=0
        __syncthreads(); F1_LOAD(A, kt +  96); F1_C(1); F1_STORE(C, 0);  // j=1
        __syncthreads(); F1_LOAD(B, kt + 128); F1_C(0); F1_STORE(A, 1);  // j=2
        __syncthreads(); F1_LOAD(C, kt + 160); F1_C(1); F1_STORE(B, 0);  // j=3
        __syncthreads(); F1_LOAD(A, kt + 192); F1_C(0); F1_STORE(C, 1);  // j=4
        __syncthreads(); F1_LOAD(B, kt + 224); F1_C(1); F1_STORE(A, 0);  // j=5
    }
    // tail: phase 30 (buf0, store B[step31]->buf1), phase 31 (buf1)
    __syncthreads(); F1_C(0); F1_STORE(B, 1);
    __syncthreads(); F1_C(1);

#undef F1_LOAD
#undef F1_STORE
#undef F1_C

    size_t rowbase = (size_t)(base + tt * 128);
    #pragma unroll
    for (int m = 0; m < 4; ++m)
        #pragma unroll
        for (int n = 0; n < 2; ++n)
            #pragma unroll
            for (int rr = 0; rr < 4; ++rr) {
                int lrow = wr * 64 + m * 16 + fg * 4 + rr;
                int col  = it * 64 + wc * 32 + n * 16 + fr;
                float v = silu_f(a1[m][n][rr]) * a3[m][n][rr];
                act[(rowbase + lrow) * ID + col] = f2bf(v);
            }
}

// ---------------- Kernel 5: FFN2 (R9-exact champion, NO setprio: ht-fast, depth-3) ----------------
// 1D grid 1024: e = bid&7, r = bid>>3, ht = r&15 (FAST), tt = r>>4.
// Only ~1 block/CU -> no inter-block arbitration; setprio hurt here (R15 A/B). ~34 us.
__global__ __launch_bounds__(256) void ffn2_kernel(
    const unsigned short* __restrict__ act, const float* __restrict__ w2,
    const int* __restrict__ counts, const int* __restrict__ offs,
    const int* __restrict__ slot_token, const float* __restrict__ slot_weight,
    float* __restrict__ out)
{
    int bid = blockIdx.x;
    int e = bid & 7;
    int r = bid >> 3;
    int ht = r & 15, tt = r >> 4;
    int cnt = counts[e];
    if (tt * 128 >= cnt) return;
    int base = offs[e];

    __shared__ unsigned short As[2][128][40];
    __shared__ unsigned short Bs[2][64][40];

    int t = threadIdx.x;
    int ar = t >> 1, as = (t & 1) * 16;
    const unsigned short* aptr = act + (size_t)(base + tt * 128 + ar) * ID;
    int wrow = t >> 2, ws0 = t & 3;
    const float* w2ptr = w2 + ((size_t)e * HD + (size_t)ht * 64 + wrow) * ID;

    int wid = t >> 6, lane = t & 63;
    int wr = wid >> 1, wc = wid & 1;
    int fr = lane & 15, fg = lane >> 4;

    f32x4 acc[4][2];
    #pragma unroll
    for (int m = 0; m < 4; ++m)
        #pragma unroll
        for (int n = 0; n < 2; ++n) acc[m][n] = (f32x4){0.f, 0.f, 0.f, 0.f};

    uint4 Aa0, Aa1, Ba0, Ba1, Ca0, Ca1;
    float4 Ab0, Ab1, Bb0, Bb1, Cb0, Cb1;

#define F2_LOAD(S, KT) do { \
    S##a0 = *(const uint4*)(aptr + (KT) + as); \
    S##a1 = *(const uint4*)(aptr + (KT) + as + 8); \
    S##b0 = *(const float4*)(w2ptr + (KT) + ws0 * 4); \
    S##b1 = *(const float4*)(w2ptr + (KT) + (ws0 + 4) * 4); \
} while (0)
#define F2_STORE(S, B) do { \
    *(uint4*)&As[B][ar][as] = S##a0; \
    *(uint4*)&As[B][ar][as + 8] = S##a1; \
    st_bf4(&Bs[B][wrow][ws0 * 4], S##b0); \
    st_bf4(&Bs[B][wrow][(ws0 + 4) * 4], S##b1); \
} while (0)
#define F2_C(B) do { \
    bf16x8 af[4], bf[2]; \
    _Pragma("unroll") for (int m = 0; m < 4; ++m) \
        af[m] = *(const bf16x8*)&As[B][wr * 64 + m * 16 + fr][fg * 8]; \
    _Pragma("unroll") for (int n = 0; n < 2; ++n) \
        bf[n] = *(const bf16x8*)&Bs[B][wc * 32 + n * 16 + fr][fg * 8]; \
    _Pragma("unroll") for (int m = 0; m < 4; ++m) \
        _Pragma("unroll") for (int n = 0; n < 2; ++n) \
            acc[m][n] = __builtin_amdgcn_mfma_f32_16x16x32_bf16(af[m], bf[n], acc[m][n], 0, 0, 0); \
} while (0)

    // prologue
    F2_LOAD(A, 0);
    F2_LOAD(B, 32);
    F2_STORE(A, 0);

    // main loop: phases 0..59 (o = 0..9); loads reach step 61 (offset 1952)
    for (int o = 0; o < 10; ++o) {
        int kt = o * 192;
        __syncthreads(); F2_LOAD(C, kt +  64); F2_C(0); F2_STORE(B, 1);
        __syncthreads(); F2_LOAD(A, kt +  96); F2_C(1); F2_STORE(C, 0);
        __syncthreads(); F2_LOAD(B, kt + 128); F2_C(0); F2_STORE(A, 1);
        __syncthreads(); F2_LOAD(C, kt + 160); F2_C(1); F2_STORE(B, 0);
        __syncthreads(); F2_LOAD(A, kt + 192); F2_C(0); F2_STORE(C, 1);
        __syncthreads(); F2_LOAD(B, kt + 224); F2_C(1); F2_STORE(A, 0);
    }
    // tail: phases 60..63 (loads for steps 62, 63 at phases 60, 61)
    __syncthreads(); F2_LOAD(C, 1984); F2_C(0); F2_STORE(B, 1);  // p=60
    __syncthreads(); F2_LOAD(A, 2016); F2_C(1); F2_STORE(C, 0);  // p=61
    __syncthreads();                   F2_C(0); F2_STORE(A, 1);  // p=62
    __syncthreads();                   F2_C(1);                  // p=63

#undef F2_LOAD
#undef F2_STORE
#undef F2_C

    #pragma unroll
    for (int m = 0; m < 4; ++m)
        #pragma unroll
        for (int rr = 0; rr < 4; ++rr) {
            int grow = tt * 128 + wr * 64 + m * 16 + fg * 4 + rr;
            if (grow < cnt) {
                int tok  = slot_token[base + grow];
                float wv = slot_weight[base + grow];
                float* orow = out + (size_t)tok * HD + ht * 64 + wc * 32;
                #pragma unroll
                for (int n = 0; n < 2; ++n)
                    atomicAdd(&orow[n * 16 + fr], wv * acc[m][n][rr]);
            }
        }
}

// ---------------- host launch ----------------
extern "C" void kernel_launch(void* const* d_in, const int* in_sizes, int n_in,
                              void* d_out, int out_size, void* d_ws, size_t ws_size,
                              hipStream_t stream)
{
    const float* x  = (const float*)d_in[0];  // (1,1024,1024)
    const float* gw = (const float*)d_in[1];  // (8,1024)
    const float* w1 = (const float*)d_in[2];  // (8,2048,1024)
    const float* w2 = (const float*)d_in[3];  // (8,1024,2048)
    const float* w3 = (const float*)d_in[4];  // (8,2048,1024)
    float* out = (float*)d_out;

    char* w = (char*)d_ws;
    int*   counts      = (int*)(w + 0);
    int*   offs        = (int*)(w + 64);
    int*   cursor      = (int*)(w + 128);
    int*   sel         = (int*)(w + 256);
    float* wgt         = (float*)(w + 256 + 8192);
    int*   slot_token  = (int*)(w + 16640);
    float* slot_weight = (float*)(w + 16640 + 4 * MAXSLOT);
    unsigned short* xbf = (unsigned short*)(w + 65536);               // 2 MB
    unsigned short* act = (unsigned short*)(w + 65536 + 2 * TT * HD); // 12.6 MB

    hipMemsetAsync(counts, 0, 64, stream);
    hipMemsetAsync(d_out, 0, (size_t)TT * HD * sizeof(float), stream);

    gate_kernel<<<TT / 4, 256, 0, stream>>>(x, gw, sel, wgt, counts, xbf);
    offsets_kernel<<<1, 1, 0, stream>>>(counts, offs, cursor);
    scatter_kernel<<<TT / 256, 256, 0, stream>>>(sel, wgt, cursor, slot_token, slot_weight);
    ffn1_kernel<<<2048, 256, 0, stream>>>(xbf, w1, w3, counts, offs, slot_token, act);
    ffn2_kernel<<<1024, 256, 0, stream>>>(act, w2, counts, offs, slot_token, slot_weight, out);
}

// Round 17
// 136.514 us; speedup vs baseline: 1.0239x; 1.0239x over previous
//
#include <hip/hip_runtime.h>
#include <hip/hip_bf16.h>
#include <math.h>

// Problem constants
#define TT 1024      // tokens (B*S)
#define HD 1024      // hidden
#define NE 8         // experts
#define ID 2048      // intermediate
#define MAXSLOT 3072
constexpr float JEPS = 0.01f;

typedef __attribute__((ext_vector_type(8))) short bf16x8;
typedef __attribute__((ext_vector_type(4))) float f32x4;

__device__ __forceinline__ float silu_f(float v) {
    return v / (1.f + expf(-v));
}

__device__ __forceinline__ unsigned short f2bf(float f) {
    unsigned int u = __float_as_uint(f);
    u += 0x7FFF + ((u >> 16) & 1);
    return (unsigned short)(u >> 16);
}

// packed fp32x4 -> bf16x4 store (v_cvt_pk_bf16_f32 path), p 8B aligned
__device__ __forceinline__ void st_bf4(unsigned short* p, float4 v) {
    __hip_bfloat162 lo = __float22bfloat162_rn(make_float2(v.x, v.y));
    __hip_bfloat162 hi = __float22bfloat162_rn(make_float2(v.z, v.w));
    union { __hip_bfloat162 h[2]; uint2 q; } pk;
    pk.h[0] = lo; pk.h[1] = hi;
    *(uint2*)p = pk.q;
}

// ---------------- Kernel 1: gating (one wave per token) + x->bf16 fused ----------------
__global__ __launch_bounds__(256) void gate_kernel(
    const float* __restrict__ x, const float* __restrict__ gw,
    int* __restrict__ sel, float* __restrict__ wgt, int* __restrict__ counts,
    unsigned short* __restrict__ xbf)
{
    int wave = threadIdx.x >> 6;
    int lane = threadIdx.x & 63;
    int t = blockIdx.x * 4 + wave;

    const float4* x4 = (const float4*)(x + (size_t)t * HD);
    const float4* g4 = (const float4*)gw;

    float acc[8] = {0.f,0.f,0.f,0.f,0.f,0.f,0.f,0.f};
    #pragma unroll
    for (int c = 0; c < 4; ++c) {
        float4 xv = x4[lane + c * 64];
        st_bf4(&xbf[(size_t)t * HD + (size_t)(lane + c * 64) * 4], xv);
        #pragma unroll
        for (int e = 0; e < 8; ++e) {
            float4 gv = g4[e * 256 + lane + c * 64];
            acc[e] += xv.x*gv.x + xv.y*gv.y + xv.z*gv.z + xv.w*gv.w;
        }
    }
    #pragma unroll
    for (int e = 0; e < 8; ++e) {
        float v = acc[e];
        #pragma unroll
        for (int off = 32; off > 0; off >>= 1) v += __shfl_xor(v, off, 64);
        acc[e] = v;
    }

    if (lane == 0) {
        float s[8];
        #pragma unroll
        for (int e = 0; e < 8; ++e) s[e] = acc[e];

        int i0 = 0; float t1 = s[0];
        #pragma unroll
        for (int e = 1; e < 8; ++e) { if (s[e] > t1) { t1 = s[e]; i0 = e; } }
        int i1 = -1; float t2 = -INFINITY;
        #pragma unroll
        for (int e = 0; e < 8; ++e) {
            if (e == i0) continue;
            if (s[e] > t2) { t2 = s[e]; i1 = e; }
        }

        float sum1 = 0.f;
        #pragma unroll
        for (int e = 0; e < 8; ++e) {
            if (e == i0) { sum1 += 1.f; continue; }
            float f = fmaxf(fabsf(s[e]), t1);
            bool masked = (t1 - s[e]) > 2.f * JEPS * f;
            if (!masked) sum1 += expf(s[e] - t1);
        }
        float w0 = 1.f / sum1;

        float sum2 = 0.f;
        #pragma unroll
        for (int e = 0; e < 8; ++e) {
            if (e == i0) continue;
            if (e == i1) { sum2 += 1.f; continue; }
            float f = fmaxf(fabsf(s[e]), t2);
            bool masked = (t2 - s[e]) > 2.f * JEPS * f;
            if (!masked) sum2 += expf(s[e] - t2);
        }
        float w1v = 1.f / sum2;

        sel[t * 2 + 0] = i0; sel[t * 2 + 1] = i1;
        wgt[t * 2 + 0] = w0; wgt[t * 2 + 1] = w1v;
        atomicAdd(&counts[i0], 1);
        atomicAdd(&counts[i1], 1);
    }
}

// ---------------- Kernel 2: padded prefix offsets (pad to 128) ----------------
__global__ void offsets_kernel(const int* __restrict__ counts,
                               int* __restrict__ offs, int* __restrict__ cursor)
{
    int o = 0;
    for (int e = 0; e < NE; ++e) {
        offs[e] = o;
        cursor[e] = o;
        o += (counts[e] + 127) & ~127;
    }
}

// ---------------- Kernel 3: scatter tokens to expert slots ----------------
__global__ __launch_bounds__(256) void scatter_kernel(
    const int* __restrict__ sel, const float* __restrict__ wgt,
    int* __restrict__ cursor, int* __restrict__ slot_token,
    float* __restrict__ slot_weight)
{
    int t = blockIdx.x * 256 + threadIdx.x;
    #pragma unroll
    for (int j = 0; j < 2; ++j) {
        int e = sel[t * 2 + j];
        int pos = atomicAdd(&cursor[e], 1);
        slot_token[pos] = t;
        slot_weight[pos] = wgt[t * 2 + j];
    }
}

// ---------------- Kernel 4: FFN1 (R15-exact: it-fast, depth-3, +setprio) ----------------
// 1D grid 2048: e = bid&7 (XCD), r = bid>>3, it = r&31 (FAST), tt = r>>5.
// Tile 128 slots x 64 intermediate, BK=32, 32 K-steps; 3 reg sets over 2 LDS bufs.
// Phase p: barrier; LOAD set[(p+2)%3]; COMPUTE buf[p%2]; STORE set[(p+1)%3]->buf[(p+1)%2].
__global__ __launch_bounds__(256) void ffn1_kernel(
    const unsigned short* __restrict__ xbf, const float* __restrict__ w1,
    const float* __restrict__ w3, const int* __restrict__ counts,
    const int* __restrict__ offs, const int* __restrict__ slot_token,
    unsigned short* __restrict__ act)
{
    int bid = blockIdx.x;
    int e = bid & 7;
    int r = bid >> 3;
    int it = r & 31, tt = r >> 5;
    int cnt = counts[e];
    if (tt * 128 >= cnt) return;
    int base = offs[e];

    __shared__ unsigned short Xs[2][128][40];
    __shared__ unsigned short W1s[2][64][40];
    __shared__ unsigned short W3s[2][64][40];

    int t = threadIdx.x;
    int xr = t >> 1, xs = (t & 1) * 16;
    int srow = tt * 128 + xr;
    int tok = (srow < cnt) ? slot_token[base + srow] : slot_token[base];
    const unsigned short* xptr = xbf + (size_t)tok * HD;
    int wrow = t >> 2, ws0 = t & 3;
    const float* w1ptr = w1 + ((size_t)e * ID + (size_t)it * 64 + wrow) * HD;
    const float* w3ptr = w3 + ((size_t)e * ID + (size_t)it * 64 + wrow) * HD;

    int wid = t >> 6, lane = t & 63;
    int wr = wid >> 1, wc = wid & 1;
    int fr = lane & 15, fg = lane >> 4;

    f32x4 a1[4][2], a3[4][2];
    #pragma unroll
    for (int m = 0; m < 4; ++m)
        #pragma unroll
        for (int n = 0; n < 2; ++n) {
            a1[m][n] = (f32x4){0.f, 0.f, 0.f, 0.f};
            a3[m][n] = (f32x4){0.f, 0.f, 0.f, 0.f};
        }

    // three named register sets (no runtime indexing)
    uint4 Axa, Axb, Bxa, Bxb, Cxa, Cxb;
    float4 Aw1a, Aw1b, Aw3a, Aw3b;
    float4 Bw1a, Bw1b, Bw3a, Bw3b;
    float4 Cw1a, Cw1b, Cw3a, Cw3b;

#define F1_LOAD(S, KT) do { \
    S##xa  = *(const uint4*)(xptr + (KT) + xs); \
    S##xb  = *(const uint4*)(xptr + (KT) + xs + 8); \
    S##w1a = *(const float4*)(w1ptr + (KT) + ws0 * 4); \
    S##w1b = *(const float4*)(w1ptr + (KT) + (ws0 + 4) * 4); \
    S##w3a = *(const float4*)(w3ptr + (KT) + ws0 * 4); \
    S##w3b = *(const float4*)(w3ptr + (KT) + (ws0 + 4) * 4); \
} while (0)
#define F1_STORE(S, B) do { \
    *(uint4*)&Xs[B][xr][xs] = S##xa; \
    *(uint4*)&Xs[B][xr][xs + 8] = S##xb; \
    st_bf4(&W1s[B][wrow][ws0 * 4], S##w1a); \
    st_bf4(&W1s[B][wrow][(ws0 + 4) * 4], S##w1b); \
    st_bf4(&W3s[B][wrow][ws0 * 4], S##w3a); \
    st_bf4(&W3s[B][wrow][(ws0 + 4) * 4], S##w3b); \
} while (0)
#define F1_C(B) do { \
    bf16x8 af[4], b1f[2], b3f[2]; \
    _Pragma("unroll") for (int m = 0; m < 4; ++m) \
        af[m] = *(const bf16x8*)&Xs[B][wr * 64 + m * 16 + fr][fg * 8]; \
    _Pragma("unroll") for (int n = 0; n < 2; ++n) { \
        b1f[n] = *(const bf16x8*)&W1s[B][wc * 32 + n * 16 + fr][fg * 8]; \
        b3f[n] = *(const bf16x8*)&W3s[B][wc * 32 + n * 16 + fr][fg * 8]; } \
    __builtin_amdgcn_s_setprio(1); \
    _Pragma("unroll") for (int m = 0; m < 4; ++m) \
        _Pragma("unroll") for (int n = 0; n < 2; ++n) { \
            a1[m][n] = __builtin_amdgcn_mfma_f32_16x16x32_bf16(af[m], b1f[n], a1[m][n], 0, 0, 0); \
            a3[m][n] = __builtin_amdgcn_mfma_f32_16x16x32_bf16(af[m], b3f[n], a3[m][n], 0, 0, 0); } \
    __builtin_amdgcn_s_setprio(0); \
} while (0)

    // prologue: step0 -> A, step1 -> B; stage A into buf0
    F1_LOAD(A, 0);
    F1_LOAD(B, 32);
    F1_STORE(A, 0);

    // main loop: phases p = 6*o + j, o = 0..4 (steps 0..29); loads reach step 31
    for (int o = 0; o < 5; ++o) {
        int kt = o * 192;
        __syncthreads(); F1_LOAD(C, kt +  64); F1_C(0); F1_STORE(B, 1);  // j=0
        __syncthreads(); F1_LOAD(A, kt +  96); F1_C(1); F1_STORE(C, 0);  // j=1
        __syncthreads(); F1_LOAD(B, kt + 128); F1_C(0); F1_STORE(A, 1);  // j=2
        __syncthreads(); F1_LOAD(C, kt + 160); F1_C(1); F1_STORE(B, 0);  // j=3
        __syncthreads(); F1_LOAD(A, kt + 192); F1_C(0); F1_STORE(C, 1);  // j=4
        __syncthreads(); F1_LOAD(B, kt + 224); F1_C(1); F1_STORE(A, 0);  // j=5
    }
    // tail: phase 30 (buf0, store B[step31]->buf1), phase 31 (buf1)
    __syncthreads(); F1_C(0); F1_STORE(B, 1);
    __syncthreads(); F1_C(1);

#undef F1_LOAD
#undef F1_STORE
#undef F1_C

    size_t rowbase = (size_t)(base + tt * 128);
    #pragma unroll
    for (int m = 0; m < 4; ++m)
        #pragma unroll
        for (int n = 0; n < 2; ++n)
            #pragma unroll
            for (int rr = 0; rr < 4; ++rr) {
                int lrow = wr * 64 + m * 16 + fg * 4 + rr;
                int col  = it * 64 + wc * 32 + n * 16 + fr;
                float v = silu_f(a1[m][n][rr]) * a3[m][n][rr];
                act[(rowbase + lrow) * ID + col] = f2bf(v);
            }
}

// ---------------- Kernel 5: FFN2 (R15-exact: ht-fast, M=128, depth-3, +setprio) ----------------
// 1D grid 1024: e = bid&7, r = bid>>3, ht = r&15 (FAST), tt = r>>4.
// Tile 128 slots x 64 hidden, K=2048, 64 K-steps; 3 reg sets over 2 LDS bufs.
__global__ __launch_bounds__(256) void ffn2_kernel(
    const unsigned short* __restrict__ act, const float* __restrict__ w2,
    const int* __restrict__ counts, const int* __restrict__ offs,
    const int* __restrict__ slot_token, const float* __restrict__ slot_weight,
    float* __restrict__ out)
{
    int bid = blockIdx.x;
    int e = bid & 7;
    int r = bid >> 3;
    int ht = r & 15, tt = r >> 4;
    int cnt = counts[e];
    if (tt * 128 >= cnt) return;
    int base = offs[e];

    __shared__ unsigned short As[2][128][40];
    __shared__ unsigned short Bs[2][64][40];

    int t = threadIdx.x;
    int ar = t >> 1, as = (t & 1) * 16;
    const unsigned short* aptr = act + (size_t)(base + tt * 128 + ar) * ID;
    int wrow = t >> 2, ws0 = t & 3;
    const float* w2ptr = w2 + ((size_t)e * HD + (size_t)ht * 64 + wrow) * ID;

    int wid = t >> 6, lane = t & 63;
    int wr = wid >> 1, wc = wid & 1;
    int fr = lane & 15, fg = lane >> 4;

    f32x4 acc[4][2];
    #pragma unroll
    for (int m = 0; m < 4; ++m)
        #pragma unroll
        for (int n = 0; n < 2; ++n) acc[m][n] = (f32x4){0.f, 0.f, 0.f, 0.f};

    uint4 Aa0, Aa1, Ba0, Ba1, Ca0, Ca1;
    float4 Ab0, Ab1, Bb0, Bb1, Cb0, Cb1;

#define F2_LOAD(S, KT) do { \
    S##a0 = *(const uint4*)(aptr + (KT) + as); \
    S##a1 = *(const uint4*)(aptr + (KT) + as + 8); \
    S##b0 = *(const float4*)(w2ptr + (KT) + ws0 * 4); \
    S##b1 = *(const float4*)(w2ptr + (KT) + (ws0 + 4) * 4); \
} while (0)
#define F2_STORE(S, B) do { \
    *(uint4*)&As[B][ar][as] = S##a0; \
    *(uint4*)&As[B][ar][as + 8] = S##a1; \
    st_bf4(&Bs[B][wrow][ws0 * 4], S##b0); \
    st_bf4(&Bs[B][wrow][(ws0 + 4) * 4], S##b1); \
} while (0)
#define F2_C(B) do { \
    bf16x8 af[4], bf[2]; \
    _Pragma("unroll") for (int m = 0; m < 4; ++m) \
        af[m] = *(const bf16x8*)&As[B][wr * 64 + m * 16 + fr][fg * 8]; \
    _Pragma("unroll") for (int n = 0; n < 2; ++n) \
        bf[n] = *(const bf16x8*)&Bs[B][wc * 32 + n * 16 + fr][fg * 8]; \
    __builtin_amdgcn_s_setprio(1); \
    _Pragma("unroll") for (int m = 0; m < 4; ++m) \
        _Pragma("unroll") for (int n = 0; n < 2; ++n) \
            acc[m][n] = __builtin_amdgcn_mfma_f32_16x16x32_bf16(af[m], bf[n], acc[m][n], 0, 0, 0); \
    __builtin_amdgcn_s_setprio(0); \
} while (0)

    // prologue
    F2_LOAD(A, 0);
    F2_LOAD(B, 32);
    F2_STORE(A, 0);

    // main loop: phases 0..59 (o = 0..9); loads reach step 61 (offset 1952)
    for (int o = 0; o < 10; ++o) {
        int kt = o * 192;
        __syncthreads(); F2_LOAD(C, kt +  64); F2_C(0); F2_STORE(B, 1);
        __syncthreads(); F2_LOAD(A, kt +  96); F2_C(1); F2_STORE(C, 0);
        __syncthreads(); F2_LOAD(B, kt + 128); F2_C(0); F2_STORE(A, 1);
        __syncthreads(); F2_LOAD(C, kt + 160); F2_C(1); F2_STORE(B, 0);
        __syncthreads(); F2_LOAD(A, kt + 192); F2_C(0); F2_STORE(C, 1);
        __syncthreads(); F2_LOAD(B, kt + 224); F2_C(1); F2_STORE(A, 0);
    }
    // tail: phases 60..63 (loads for steps 62, 63 at phases 60, 61)
    __syncthreads(); F2_LOAD(C, 1984); F2_C(0); F2_STORE(B, 1);  // p=60
    __syncthreads(); F2_LOAD(A, 2016); F2_C(1); F2_STORE(C, 0);  // p=61
    __syncthreads();                   F2_C(0); F2_STORE(A, 1);  // p=62
    __syncthreads();                   F2_C(1);                  // p=63

#undef F2_LOAD
#undef F2_STORE
#undef F2_C

    #pragma unroll
    for (int m = 0; m < 4; ++m)
        #pragma unroll
        for (int rr = 0; rr < 4; ++rr) {
            int grow = tt * 128 + wr * 64 + m * 16 + fg * 4 + rr;
            if (grow < cnt) {
                int tok  = slot_token[base + grow];
                float wv = slot_weight[base + grow];
                float* orow = out + (size_t)tok * HD + ht * 64 + wc * 32;
                #pragma unroll
                for (int n = 0; n < 2; ++n)
                    atomicAdd(&orow[n * 16 + fr], wv * acc[m][n][rr]);
            }
        }
}

// ---------------- host launch ----------------
extern "C" void kernel_launch(void* const* d_in, const int* in_sizes, int n_in,
                              void* d_out, int out_size, void* d_ws, size_t ws_size,
                              hipStream_t stream)
{
    const float* x  = (const float*)d_in[0];  // (1,1024,1024)
    const float* gw = (const float*)d_in[1];  // (8,1024)
    const float* w1 = (const float*)d_in[2];  // (8,2048,1024)
    const float* w2 = (const float*)d_in[3];  // (8,1024,2048)
    const float* w3 = (const float*)d_in[4];  // (8,2048,1024)
    float* out = (float*)d_out;

    char* w = (char*)d_ws;
    int*   counts      = (int*)(w + 0);
    int*   offs        = (int*)(w + 64);
    int*   cursor      = (int*)(w + 128);
    int*   sel         = (int*)(w + 256);
    float* wgt         = (float*)(w + 256 + 8192);
    int*   slot_token  = (int*)(w + 16640);
    float* slot_weight = (float*)(w + 16640 + 4 * MAXSLOT);
    unsigned short* xbf = (unsigned short*)(w + 65536);               // 2 MB
    unsigned short* act = (unsigned short*)(w + 65536 + 2 * TT * HD); // 12.6 MB

    hipMemsetAsync(counts, 0, 64, stream);
    hipMemsetAsync(d_out, 0, (size_t)TT * HD * sizeof(float), stream);

    gate_kernel<<<TT / 4, 256, 0, stream>>>(x, gw, sel, wgt, counts, xbf);
    offsets_kernel<<<1, 1, 0, stream>>>(counts, offs, cursor);
    scatter_kernel<<<TT / 256, 256, 0, stream>>>(sel, wgt, cursor, slot_token, slot_weight);
    ffn1_kernel<<<2048, 256, 0, stream>>>(xbf, w1, w3, counts, offs, slot_token, act);
    ffn2_kernel<<<1024, 256, 0, stream>>>(act, w2, counts, offs, slot_token, slot_weight, out);
}